// Round 5
// baseline (239.743 us; speedup 1.0000x reference)
//
#include <hip/hip_runtime.h>
#include <stdint.h>
#include <math.h>

// Problem constants (match reference setup_inputs)
#define IMGF   512.0f
#define A_N    49104
#define B_N    8
#define C_N    80
#define K_N    256
#define IOU_T  0.5f
#define NBIN   16384     // linear bins: bin = (int)(score * 16384), clamped
#define CAP    2048      // per-batch candidate capacity (nc expected ~300)
#define NPAIR  (B_N * A_N / 2)   // 196416 anchor pairs

__device__ __forceinline__ int bin_of(uint32_t key) {
    float s = __uint_as_float(key);          // s in [0,1)
    int b = (int)(s * 16384.0f);
    return b > 16383 ? 16383 : b;
}

// ---------------------------------------------------------------------------
// Kernel A: persistent 4-lane groups, 2 anchors (one contiguous 640B pair-row)
// per iteration, register double-buffered across grid-stride iterations so the
// next 10 float4 loads are in flight while the current pair is reduced.
// Reduction: fmax tree -> cross-lane max (2 shuffles) -> first-argmax recovery
// by equality (in-lane ascending class order, then min across lanes).
// ---------------------------------------------------------------------------
__global__ __launch_bounds__(256) void score_kernel(
    const float* __restrict__ logits,
    uint32_t* __restrict__ keys,
    int* __restrict__ labels)
{
    const int tid  = threadIdx.x;
    const int lane = tid & 63;
    const int grp  = lane >> 2, j = lane & 3;
    const int ggid = blockIdx.x * 64 + (tid >> 6) * 16 + grp;
    const int NGt  = gridDim.x * 64;         // total groups (<= NPAIR)

    float4 c[10];
    int p = ggid;                            // always < NPAIR for 768 blocks
    {
        const float4* r = (const float4*)(logits + (size_t)(2 * p) * C_N);
#pragma unroll
        for (int k = 0; k < 5; ++k) { c[k] = r[j + 4 * k]; c[5 + k] = r[20 + j + 4 * k]; }
    }
    while (true) {
        const int pn = p + NGt;
        const bool vn = pn < NPAIR;
        float4 n[10];
        if (vn) {
            const float4* r = (const float4*)(logits + (size_t)(2 * pn) * C_N);
#pragma unroll
            for (int k = 0; k < 5; ++k) { n[k] = r[j + 4 * k]; n[5 + k] = r[20 + j + 4 * k]; }
        }
        // ---- reduce current pair p (rows 2p, 2p+1) ----
        {
            const float* f = (const float*)c;
            float m0 = f[0], m1 = f[20];
#pragma unroll
            for (int q = 1; q < 20; ++q) m0 = fmaxf(m0, f[q]);
#pragma unroll
            for (int q = 1; q < 20; ++q) m1 = fmaxf(m1, f[20 + q]);
            m0 = fmaxf(m0, __shfl_xor(m0, 1, 64));
            m0 = fmaxf(m0, __shfl_xor(m0, 2, 64));
            m1 = fmaxf(m1, __shfl_xor(m1, 1, 64));
            m1 = fmaxf(m1, __shfl_xor(m1, 2, 64));
            int cl0 = 1 << 30, cl1 = 1 << 30;
#pragma unroll
            for (int k = 0; k < 5; ++k) {
#pragma unroll
                for (int q = 0; q < 4; ++q) {
                    const int cc = (j + 4 * k) * 4 + q;      // ascending in (k,q)
                    const float v0 = ((const float*)&c[k])[q];
                    const float v1 = ((const float*)&c[5 + k])[q];
                    if (v0 == m0 && cc < cl0) cl0 = cc;
                    if (v1 == m1 && cc < cl1) cl1 = cc;
                }
            }
            { int t = __shfl_xor(cl0, 1, 64); if (t < cl0) cl0 = t;
              t = __shfl_xor(cl0, 2, 64); if (t < cl0) cl0 = t; }
            { int t = __shfl_xor(cl1, 1, 64); if (t < cl1) cl1 = t;
              t = __shfl_xor(cl1, 2, 64); if (t < cl1) cl1 = t; }
            if (j < 2) {                      // lane 0 -> row 2p, lane 1 -> row 2p+1
                const float m = (j == 0) ? m0 : m1;
                const int  cl = (j == 0) ? cl0 : cl1;
                float s = 1.0f / (1.0f + expf(-m));
                if (!(s > 0.01f)) s = 0.0f;
                const int row = 2 * p + j;
                keys[row]   = __float_as_uint(s);
                labels[row] = cl;
            }
        }
        if (!vn) break;
#pragma unroll
        for (int q = 0; q < 10; ++q) c[q] = n[q];
        p = pn;
    }
}

// ---------------------------------------------------------------------------
// Kernel B (fused): one block (1024 threads) per batch.
//   1) LDS-private 16384 LINEAR-bin histogram (low contention: ~6500 active
//      bins, peak ~40/address vs ~3000 with mantissa bins)
//   2) block suffix-scan -> exact threshold bin T (count(>T) < 256 <= count(>=T))
//   3) compact keys with bin >= T into LDS candidates (~300)
//   4) counting-rank sort by packed (key desc, idx asc) u64 == stable top_k
//   5) decode top-256 (fp-contract off), 256x256 suppression bitmask,
//      branchless serial greedy scan == reference NMS
//   6) write dets [B,K,5] ++ labels [B,K] ++ keep [B,K] as float32
// ---------------------------------------------------------------------------
__global__ __launch_bounds__(1024) void select_nms_kernel(
    const uint32_t* __restrict__ keys,
    const int* __restrict__ labels,
    const float* __restrict__ regs,
    const float* __restrict__ anchors,
    float* __restrict__ out)
{
    const int b   = blockIdx.x;
    const int tid = threadIdx.x;          // 0..1023

    __shared__ uint32_t hist[NBIN];                 // 64 KB
    __shared__ int ssum[1024];                      // 4 KB
    __shared__ int sh_T, sh_nc;
    __shared__ unsigned long long cand[CAP];        // 16 KB
    __shared__ unsigned long long sorted[K_N];      // 2 KB
    __shared__ float4 sbox[K_N];
    __shared__ float  sscore[K_N];
    __shared__ int    slab[K_N];
    __shared__ unsigned long long supr[K_N][4];     // 8 KB
    __shared__ unsigned long long keepw[4];

    const uint32_t* kb = keys + (size_t)b * A_N;
    const uint4* kb4 = (const uint4*)kb;            // A_N % 4 == 0, 16B aligned
    const int N4 = A_N / 4;                         // 12276

    // ---- Phase 1: histogram (linear bins) ----
    for (int i = tid; i < NBIN; i += 1024) hist[i] = 0;
    __syncthreads();
    for (int i = tid; i < N4; i += 1024) {
        uint4 v = kb4[i];
        atomicAdd(&hist[bin_of(v.x)], 1u);
        atomicAdd(&hist[bin_of(v.y)], 1u);
        atomicAdd(&hist[bin_of(v.z)], 1u);
        atomicAdd(&hist[bin_of(v.w)], 1u);
    }
    __syncthreads();

    // ---- Phase 2: threshold bin via suffix scan ----
    const int lo = tid * (NBIN / 1024);             // 16 bins/thread
    int seg = 0;
#pragma unroll
    for (int q = 0; q < NBIN / 1024; ++q) seg += (int)hist[lo + q];
    ssum[tid] = seg;
    __syncthreads();
    for (int off = 1; off < 1024; off <<= 1) {      // inclusive suffix sum
        int v = (tid + off < 1024) ? ssum[tid + off] : 0;
        __syncthreads();
        ssum[tid] += v;
        __syncthreads();
    }
    int above = ssum[tid] - seg;                    // strictly-higher segments
    if (above < K_N && above + seg >= K_N) {        // exactly one thread true
        int cum = above;
        for (int bin = lo + NBIN / 1024 - 1; bin >= lo; --bin) {
            int c = (int)hist[bin];
            if (cum + c >= K_N) { sh_T = bin; break; }
            cum += c;
        }
    }
    if (tid == 0) sh_nc = 0;
    __syncthreads();
    const int T = sh_T;

    // ---- Phase 3: compact candidates (bin >= T) ----
    for (int i = tid; i < N4; i += 1024) {
        uint4 v = kb4[i];
        uint32_t ks[4] = { v.x, v.y, v.z, v.w };
#pragma unroll
        for (int q = 0; q < 4; ++q) {
            if (bin_of(ks[q]) >= T) {
                int p = atomicAdd(&sh_nc, 1);
                if (p < CAP)
                    cand[p] = ((unsigned long long)ks[q] << 32)
                            | (unsigned long long)(0xFFFFFFFFu - (uint32_t)(4 * i + q));
            }
        }
    }
    if (tid < K_N) sorted[tid] = 0ull;
    __syncthreads();
    int nc = sh_nc; if (nc > CAP) nc = CAP;

    // ---- Phase 4: counting-rank sort (broadcast reads, no barriers) ----
    for (int i = tid; i < nc; i += 1024) {
        unsigned long long me = cand[i];
        int r = 0;
        for (int jq = 0; jq < nc; ++jq) r += (cand[jq] > me);
        if (r < K_N) sorted[r] = me;
    }
    __syncthreads();

    // ---- Phase 5: decode top-256 boxes (threads 0..255) ----
    if (tid < K_N) {
#pragma clang fp contract(off)
        unsigned long long cv = sorted[tid];
        uint32_t key = (uint32_t)(cv >> 32);
        uint32_t ai  = 0xFFFFFFFFu - (uint32_t)cv;
        if (ai >= (uint32_t)A_N) ai = 0;   // pad entries (score 0, unkept)
        int a = (int)ai;
        float s = __uint_as_float(key);
        sscore[tid] = s;
        slab[tid]   = labels[(size_t)b * A_N + a];

        float ax0 = anchors[4 * a + 0], ay0 = anchors[4 * a + 1];
        float ax1 = anchors[4 * a + 2], ay1 = anchors[4 * a + 3];
        float aw = ax1 - ax0, ah = ay1 - ay0;
        float acx = ax0 + 0.5f * aw, acy = ay0 + 0.5f * ah;
        const float* r = regs + ((size_t)b * A_N + a) * 4;
        float dx = r[0], dy = r[1], dw = r[2], dh = r[3];
        float cx = acx + dx * aw;
        float cy = acy + dy * ah;
        dw = fminf(fmaxf(dw, -4.0f), 4.0f);
        dh = fminf(fmaxf(dh, -4.0f), 4.0f);
        float w = aw * expf(dw);
        float h = ah * expf(dh);
        float x0 = cx - 0.5f * w, y0 = cy - 0.5f * h;
        float x1 = cx + 0.5f * w, y1 = cy + 0.5f * h;
        x0 = fminf(fmaxf(x0, 0.0f), IMGF);
        y0 = fminf(fmaxf(y0, 0.0f), IMGF);
        x1 = fminf(fmaxf(x1, 0.0f), IMGF);
        y1 = fminf(fmaxf(y1, 0.0f), IMGF);
        sbox[tid] = make_float4(x0, y0, x1, y1);
    }
    __syncthreads();

    // ---- Phase 6a: suppression matrix, one u64 word per thread ----
    {
#pragma clang fp contract(off)
        const int row = tid & 255, gq = tid >> 8;   // word gq of row
        float4 bi = sbox[row];
        float areai = fmaxf(bi.z - bi.x, 0.0f) * fmaxf(bi.w - bi.y, 0.0f);
        unsigned long long m = 0;
        const int jlo = gq * 64, jhi = jlo + 64;
        int start = row + 1 > jlo ? row + 1 : jlo;
        for (int jx = start; jx < jhi; ++jx) {
            float4 bj = sbox[jx];
            float areaj = fmaxf(bj.z - bj.x, 0.0f) * fmaxf(bj.w - bj.y, 0.0f);
            float lx = fmaxf(bi.x, bj.x), ly = fmaxf(bi.y, bj.y);
            float rx = fminf(bi.z, bj.z), ry = fminf(bi.w, bj.w);
            float iw = fmaxf(rx - lx, 0.0f), ih = fmaxf(ry - ly, 0.0f);
            float inter = iw * ih;
            float uni = areai + areaj - inter;
            float iou = inter / fmaxf(uni, 1e-8f);
            if (iou > IOU_T) m |= 1ull << (jx & 63);
        }
        supr[row][gq] = m;
    }
    // keep0 = score > 0 (threads 0..255 = waves 0..3)
    if (tid < K_N) {
        unsigned long long ball = __ballot(sscore[tid] > 0.0f);
        if ((tid & 63) == 0) keepw[tid >> 6] = ball;
    }
    __syncthreads();

    // ---- Phase 6b: branchless serial greedy scan (loads hoisted) ----
    if (tid == 0) {
        unsigned long long k0 = keepw[0], k1 = keepw[1], k2 = keepw[2], k3 = keepw[3];
#define NMS_CHUNK(c, kc)                                                     \
        for (int l = 0; l < 64; ++l) {                                       \
            const int i = (c) * 64 + l;                                      \
            unsigned long long w0 = supr[i][0], w1 = supr[i][1];             \
            unsigned long long w2 = supr[i][2], w3 = supr[i][3];             \
            if ((kc >> l) & 1ull) {                                          \
                k0 &= ~w0; k1 &= ~w1; k2 &= ~w2; k3 &= ~w3;                  \
            }                                                                \
        }
        NMS_CHUNK(0, k0)
        NMS_CHUNK(1, k1)
        NMS_CHUNK(2, k2)
        NMS_CHUNK(3, k3)
#undef NMS_CHUNK
        keepw[0] = k0; keepw[1] = k1; keepw[2] = k2; keepw[3] = k3;
    }
    __syncthreads();

    // ---- Phase 7: outputs: dets [B,K,5] ++ labels [B,K] ++ keep [B,K] ----
    if (tid < K_N) {
        float keepf = ((keepw[tid >> 6] >> (tid & 63)) & 1ull) ? 1.0f : 0.0f;
        float4 bx = sbox[tid];
        float s = sscore[tid];
        float* det = out + ((size_t)b * K_N + tid) * 5;
        det[0] = bx.x * keepf;
        det[1] = bx.y * keepf;
        det[2] = bx.z * keepf;
        det[3] = bx.w * keepf;
        det[4] = s * keepf;
        out[(size_t)B_N * K_N * 5 + (size_t)b * K_N + tid] = (float)slab[tid];
        out[(size_t)B_N * K_N * 5 + (size_t)B_N * K_N + (size_t)b * K_N + tid] = keepf;
    }
}

extern "C" void kernel_launch(void* const* d_in, const int* in_sizes, int n_in,
                              void* d_out, int out_size, void* d_ws, size_t ws_size,
                              hipStream_t stream)
{
    const float* logits  = (const float*)d_in[0];   // [B,A,C] fp32
    const float* regs    = (const float*)d_in[1];   // [B,A,4] fp32
    const float* anchors = (const float*)d_in[2];   // [A,4]   fp32
    float* out = (float*)d_out;

    uint32_t* keys   = (uint32_t*)d_ws;                      // B*A u32
    int*      labels = (int*)(keys + (size_t)B_N * A_N);     // B*A i32

    // 768 blocks * 64 groups = 49152 persistent groups; ~4 pair-iterations each
    score_kernel<<<768, 256, 0, stream>>>(logits, keys, labels);
    select_nms_kernel<<<B_N, 1024, 0, stream>>>(keys, labels, regs, anchors, out);
}

// Round 6
// 237.833 us; speedup vs baseline: 1.0080x; 1.0080x over previous
//
#include <hip/hip_runtime.h>
#include <stdint.h>
#include <math.h>

// Problem constants (match reference setup_inputs)
#define IMGF   512.0f
#define A_N    49104
#define B_N    8
#define C_N    80
#define K_N    256
#define IOU_T  0.5f
#define NBIN   4096      // linear bins: bin = (int)(score * 4096), clamped
#define CAP    2048      // per-batch candidate capacity (nc expected ~310)

__device__ __forceinline__ int bin_of(uint32_t key) {
    float s = __uint_as_float(key);          // s in [0,1)
    int b = (int)(s * 4096.0f);
    return b > 4095 ? 4095 : b;
}

// ---------------------------------------------------------------------------
// Kernel A: score only — NO argmax (labels recovered later for just the 256
// selected anchors). 4 lanes per anchor, 5 float4 loads each (fully-consumed
// 64B lines per 4-lane group), 19-op fmax tree, 2 cross-lane shuffles,
// sigmoid+threshold+store on lane j==0. ~25 VALU ops per lane per anchor ->
// memory-bound by ~10x; tiny VGPR footprint -> max occupancy.
// ---------------------------------------------------------------------------
__global__ __launch_bounds__(256) void score_kernel(
    const float* __restrict__ logits,
    uint32_t* __restrict__ keys)
{
    const int tid  = threadIdx.x;
    const int lane = tid & 63;
    const int grp  = lane >> 2, j = lane & 3;
    const int g = blockIdx.x * 64 + (tid >> 6) * 16 + grp;   // anchor (flat B*A)

    const float4* p = (const float4*)(logits + (size_t)g * C_N);
    float4 v0 = p[j], v1 = p[j + 4], v2 = p[j + 8], v3 = p[j + 12], v4 = p[j + 16];
    float m = fmaxf(fmaxf(fmaxf(v0.x, v0.y), fmaxf(v0.z, v0.w)),
                    fmaxf(fmaxf(v1.x, v1.y), fmaxf(v1.z, v1.w)));
    m = fmaxf(m, fmaxf(fmaxf(v2.x, v2.y), fmaxf(v2.z, v2.w)));
    m = fmaxf(m, fmaxf(fmaxf(v3.x, v3.y), fmaxf(v3.z, v3.w)));
    m = fmaxf(m, fmaxf(fmaxf(v4.x, v4.y), fmaxf(v4.z, v4.w)));
    m = fmaxf(m, __shfl_xor(m, 1, 64));
    m = fmaxf(m, __shfl_xor(m, 2, 64));
    if (j == 0) {
        float s = 1.0f / (1.0f + expf(-m));
        if (!(s > 0.01f)) s = 0.0f;          // reference: where(s > thr, s, 0)
        keys[g] = __float_as_uint(s);        // s >= 0 -> order-preserving bits
    }
}

// ---------------------------------------------------------------------------
// Kernel B (fused): one block (1024 threads) per batch.
//   1) LDS 4096 linear-bin histogram (uint4 loads, low-contention atomics)
//   2) wave-shuffle suffix scan (2 barriers) -> exact threshold bin T
//   3) compact keys with bin >= T into LDS candidates (~310)
//   4) counting-rank sort by packed (key desc, idx asc) u64 == stable top_k
//   5) decode top-256 + argmax-recovery gather (re-read 320B logit row each)
//   6) 256x256 suppression bitmask, branchless serial greedy scan == ref NMS
//   7) write dets [B,K,5] ++ labels [B,K] ++ keep [B,K] as float32
// ---------------------------------------------------------------------------
__global__ __launch_bounds__(1024) void select_nms_kernel(
    const uint32_t* __restrict__ keys,
    const float* __restrict__ logits,
    const float* __restrict__ regs,
    const float* __restrict__ anchors,
    float* __restrict__ out)
{
    const int b   = blockIdx.x;
    const int tid = threadIdx.x;          // 0..1023
    const int lane = tid & 63, wv = tid >> 6;

    __shared__ uint32_t hist[NBIN];                 // 16 KB
    __shared__ int wtots[16];
    __shared__ int sh_T, sh_nc;
    __shared__ unsigned long long cand[CAP];        // 16 KB
    __shared__ unsigned long long sorted[K_N];      // 2 KB
    __shared__ float4 sbox[K_N];
    __shared__ float  sscore[K_N];
    __shared__ int    slab[K_N];
    __shared__ unsigned long long supr[K_N][4];     // 8 KB
    __shared__ unsigned long long keepw[4];

    const uint32_t* kb = keys + (size_t)b * A_N;
    const uint4* kb4 = (const uint4*)kb;            // A_N % 4 == 0, 16B aligned
    const int N4 = A_N / 4;                         // 12276

    // ---- Phase 1: histogram (linear bins) ----
    for (int i = tid; i < NBIN; i += 1024) hist[i] = 0;
    if (tid == 0) sh_nc = 0;
    __syncthreads();
    for (int i = tid; i < N4; i += 1024) {
        uint4 v = kb4[i];
        atomicAdd(&hist[bin_of(v.x)], 1u);
        atomicAdd(&hist[bin_of(v.y)], 1u);
        atomicAdd(&hist[bin_of(v.z)], 1u);
        atomicAdd(&hist[bin_of(v.w)], 1u);
    }
    __syncthreads();

    // ---- Phase 2: threshold bin via wave-shuffle suffix scan (2 barriers) ----
    const int lo = tid * 4;                         // 4 bins per thread
    int seg = (int)hist[lo] + (int)hist[lo + 1]
            + (int)hist[lo + 2] + (int)hist[lo + 3];
    int s1 = seg;                                   // within-wave inclusive suffix
#pragma unroll
    for (int off = 1; off < 64; off <<= 1) {
        int v = __shfl_down(s1, off, 64);
        if (lane + off < 64) s1 += v;
    }
    if (lane == 0) wtots[wv] = s1;                  // wave total
    __syncthreads();
    int wsuf = 0;
    for (int w = wv + 1; w < 16; ++w) wsuf += wtots[w];
    int above = wsuf + (s1 - seg);                  // keys in strictly-later segs
    if (above < K_N && above + seg >= K_N) {        // exactly one thread true
        int cum = above;
        for (int bin = lo + 3; bin >= lo; --bin) {
            int c = (int)hist[bin];
            if (cum + c >= K_N) { sh_T = bin; break; }
            cum += c;
        }
    }
    __syncthreads();
    const int T = sh_T;

    // ---- Phase 3: compact candidates (bin >= T) ----
    for (int i = tid; i < N4; i += 1024) {
        uint4 v = kb4[i];
        uint32_t ks[4] = { v.x, v.y, v.z, v.w };
#pragma unroll
        for (int q = 0; q < 4; ++q) {
            if (bin_of(ks[q]) >= T) {
                int p = atomicAdd(&sh_nc, 1);
                if (p < CAP)
                    cand[p] = ((unsigned long long)ks[q] << 32)
                            | (unsigned long long)(0xFFFFFFFFu - (uint32_t)(4 * i + q));
            }
        }
    }
    if (tid < K_N) sorted[tid] = 0ull;
    __syncthreads();
    int nc = sh_nc; if (nc > CAP) nc = CAP;

    // ---- Phase 4: counting-rank sort (broadcast reads, no barriers) ----
    for (int i = tid; i < nc; i += 1024) {
        unsigned long long me = cand[i];
        int r = 0;
        for (int jq = 0; jq < nc; ++jq) r += (cand[jq] > me);
        if (r < K_N) sorted[r] = me;
    }
    __syncthreads();

    // ---- Phase 5: decode top-256 + label recovery (threads 0..255) ----
    if (tid < K_N) {
#pragma clang fp contract(off)
        unsigned long long cv = sorted[tid];
        uint32_t key = (uint32_t)(cv >> 32);
        uint32_t ai  = 0xFFFFFFFFu - (uint32_t)cv;
        if (ai >= (uint32_t)A_N) ai = 0;   // pad entries (score 0, unkept)
        int a = (int)ai;
        float s = __uint_as_float(key);
        sscore[tid] = s;

        // argmax recovery: first index of max over the 80-logit row
        {
            const float4* lp = (const float4*)(logits + ((size_t)b * A_N + a) * C_N);
            float best = -INFINITY; int cls = 0;
#pragma unroll
            for (int k = 0; k < 20; ++k) {
                float4 w = lp[k];
                if (w.x > best) { best = w.x; cls = 4 * k + 0; }
                if (w.y > best) { best = w.y; cls = 4 * k + 1; }
                if (w.z > best) { best = w.z; cls = 4 * k + 2; }
                if (w.w > best) { best = w.w; cls = 4 * k + 3; }
            }
            slab[tid] = cls;
        }

        float ax0 = anchors[4 * a + 0], ay0 = anchors[4 * a + 1];
        float ax1 = anchors[4 * a + 2], ay1 = anchors[4 * a + 3];
        float aw = ax1 - ax0, ah = ay1 - ay0;
        float acx = ax0 + 0.5f * aw, acy = ay0 + 0.5f * ah;
        const float* r = regs + ((size_t)b * A_N + a) * 4;
        float dx = r[0], dy = r[1], dw = r[2], dh = r[3];
        float cx = acx + dx * aw;
        float cy = acy + dy * ah;
        dw = fminf(fmaxf(dw, -4.0f), 4.0f);
        dh = fminf(fmaxf(dh, -4.0f), 4.0f);
        float w = aw * expf(dw);
        float h = ah * expf(dh);
        float x0 = cx - 0.5f * w, y0 = cy - 0.5f * h;
        float x1 = cx + 0.5f * w, y1 = cy + 0.5f * h;
        x0 = fminf(fmaxf(x0, 0.0f), IMGF);
        y0 = fminf(fmaxf(y0, 0.0f), IMGF);
        x1 = fminf(fmaxf(x1, 0.0f), IMGF);
        y1 = fminf(fmaxf(y1, 0.0f), IMGF);
        sbox[tid] = make_float4(x0, y0, x1, y1);
    }
    __syncthreads();

    // ---- Phase 6a: suppression matrix, one u64 word per thread ----
    {
#pragma clang fp contract(off)
        const int row = tid & 255, gq = tid >> 8;   // word gq of row
        float4 bi = sbox[row];
        float areai = fmaxf(bi.z - bi.x, 0.0f) * fmaxf(bi.w - bi.y, 0.0f);
        unsigned long long m = 0;
        const int jlo = gq * 64, jhi = jlo + 64;
        int start = row + 1 > jlo ? row + 1 : jlo;
        for (int jx = start; jx < jhi; ++jx) {
            float4 bj = sbox[jx];
            float areaj = fmaxf(bj.z - bj.x, 0.0f) * fmaxf(bj.w - bj.y, 0.0f);
            float lx = fmaxf(bi.x, bj.x), ly = fmaxf(bi.y, bj.y);
            float rx = fminf(bi.z, bj.z), ry = fminf(bi.w, bj.w);
            float iw = fmaxf(rx - lx, 0.0f), ih = fmaxf(ry - ly, 0.0f);
            float inter = iw * ih;
            float uni = areai + areaj - inter;
            float iou = inter / fmaxf(uni, 1e-8f);
            if (iou > IOU_T) m |= 1ull << (jx & 63);
        }
        supr[row][gq] = m;
    }
    // keep0 = score > 0 (threads 0..255 = waves 0..3)
    if (tid < K_N) {
        unsigned long long ball = __ballot(sscore[tid] > 0.0f);
        if ((tid & 63) == 0) keepw[tid >> 6] = ball;
    }
    __syncthreads();

    // ---- Phase 6b: branchless serial greedy scan (loads hoisted) ----
    if (tid == 0) {
        unsigned long long k0 = keepw[0], k1 = keepw[1], k2 = keepw[2], k3 = keepw[3];
#define NMS_CHUNK(c, kc)                                                     \
        for (int l = 0; l < 64; ++l) {                                       \
            const int i = (c) * 64 + l;                                      \
            unsigned long long w0 = supr[i][0], w1 = supr[i][1];             \
            unsigned long long w2 = supr[i][2], w3 = supr[i][3];             \
            if ((kc >> l) & 1ull) {                                          \
                k0 &= ~w0; k1 &= ~w1; k2 &= ~w2; k3 &= ~w3;                  \
            }                                                                \
        }
        NMS_CHUNK(0, k0)
        NMS_CHUNK(1, k1)
        NMS_CHUNK(2, k2)
        NMS_CHUNK(3, k3)
#undef NMS_CHUNK
        keepw[0] = k0; keepw[1] = k1; keepw[2] = k2; keepw[3] = k3;
    }
    __syncthreads();

    // ---- Phase 7: outputs: dets [B,K,5] ++ labels [B,K] ++ keep [B,K] ----
    if (tid < K_N) {
        float keepf = ((keepw[tid >> 6] >> (tid & 63)) & 1ull) ? 1.0f : 0.0f;
        float4 bx = sbox[tid];
        float s = sscore[tid];
        float* det = out + ((size_t)b * K_N + tid) * 5;
        det[0] = bx.x * keepf;
        det[1] = bx.y * keepf;
        det[2] = bx.z * keepf;
        det[3] = bx.w * keepf;
        det[4] = s * keepf;
        out[(size_t)B_N * K_N * 5 + (size_t)b * K_N + tid] = (float)slab[tid];
        out[(size_t)B_N * K_N * 5 + (size_t)B_N * K_N + (size_t)b * K_N + tid] = keepf;
    }
}

extern "C" void kernel_launch(void* const* d_in, const int* in_sizes, int n_in,
                              void* d_out, int out_size, void* d_ws, size_t ws_size,
                              hipStream_t stream)
{
    const float* logits  = (const float*)d_in[0];   // [B,A,C] fp32
    const float* regs    = (const float*)d_in[1];   // [B,A,4] fp32
    const float* anchors = (const float*)d_in[2];   // [A,4]   fp32
    float* out = (float*)d_out;

    uint32_t* keys = (uint32_t*)d_ws;               // B*A u32 only

    const int total = B_N * A_N;                    // 392832 = 6138 * 64
    score_kernel<<<total / 64, 256, 0, stream>>>(logits, keys);
    select_nms_kernel<<<B_N, 1024, 0, stream>>>(keys, logits, regs, anchors, out);
}